// Round 1
// baseline (401.865 us; speedup 1.0000x reference)
//
#include <hip/hip_runtime.h>
#include <math.h>

#define TPB    256
#define CHUNK  1024
#define DHEAD  128
#define NB     8

// ---------------------------------------------------------------------------
// Kernel 1: per-(b,h,split) flash-decode partial.
//   Pass 1: scores for CHUNK keys into LDS (coalesced float4 K reads,
//           32-lane shuffle dot-reduce).
//   Pass 2: chunk softmax (m, l) + P·V with float4 V reads.
//   Emits unnormalized acc[128], m, l to workspace.
// ---------------------------------------------------------------------------
__global__ __launch_bounds__(TPB) void attn_partial(
    const float* __restrict__ q, const float* __restrict__ kc,
    const float* __restrict__ vc, float* __restrict__ part,
    int S, int nsplit)
{
    const int bh    = blockIdx.x;     // b*H + h
    const int split = blockIdx.y;
    const int tid   = threadIdx.x;
    const int s0    = split * CHUNK;

    __shared__ float sc[CHUNK];          // 4 KB scores
    __shared__ float qs[DHEAD];          // 512 B
    __shared__ float red[8];             // reduce scratch
    __shared__ float accs[8][DHEAD];     // 4 KB PV group partials

    if (tid < DHEAD) qs[tid] = q[(size_t)bh * DHEAD + tid];
    __syncthreads();

    const int lane32 = tid & 31;         // float4 slot within a row (32*4=128)
    const int grp    = tid >> 5;         // 0..7
    const float4 q4  = ((const float4*)qs)[lane32];
    const float scale = 0.088388347648318447f;  // 1/sqrt(128)

    // ---- pass 1: scores ----
    const float* Kbase = kc + ((size_t)bh * S + s0) * DHEAD;
    for (int it = 0; it < CHUNK / 8; ++it) {
        const int row = it * 8 + grp;
        const float4 k4 = ((const float4*)(Kbase + (size_t)row * DHEAD))[lane32];
        float p = q4.x * k4.x + q4.y * k4.y + q4.z * k4.z + q4.w * k4.w;
        #pragma unroll
        for (int off = 16; off > 0; off >>= 1) p += __shfl_xor(p, off);
        if (lane32 == 0) sc[row] = p * scale;
    }
    __syncthreads();

    // ---- chunk max ----
    float m = -INFINITY;
    for (int i = tid; i < CHUNK; i += TPB) m = fmaxf(m, sc[i]);
    #pragma unroll
    for (int off = 32; off > 0; off >>= 1) m = fmaxf(m, __shfl_xor(m, off));
    if ((tid & 63) == 0) red[tid >> 6] = m;
    __syncthreads();
    m = fmaxf(fmaxf(red[0], red[1]), fmaxf(red[2], red[3]));

    // ---- exp + sum (writes sc in place) ----
    float lsum = 0.f;
    for (int i = tid; i < CHUNK; i += TPB) {
        const float e = expf(sc[i] - m);
        sc[i] = e;
        lsum += e;
    }
    #pragma unroll
    for (int off = 32; off > 0; off >>= 1) lsum += __shfl_xor(lsum, off);
    if ((tid & 63) == 0) red[4 + (tid >> 6)] = lsum;
    __syncthreads();                      // also makes sc[] writes visible
    lsum = red[4] + red[5] + red[6] + red[7];

    // ---- pass 2: P·V. group g owns s in [g*128, (g+1)*128), lanes own 4 cols
    const float* Vbase = vc + ((size_t)bh * S + s0) * DHEAD;
    float4 acc = make_float4(0.f, 0.f, 0.f, 0.f);
    const int sBeg = grp * (CHUNK / 8);
    for (int s = sBeg; s < sBeg + CHUNK / 8; ++s) {
        const float  p  = sc[s];          // LDS broadcast within 32-lane group
        const float4 v4 = ((const float4*)(Vbase + (size_t)s * DHEAD))[lane32];
        acc.x += p * v4.x; acc.y += p * v4.y;
        acc.z += p * v4.z; acc.w += p * v4.w;
    }
    ((float4*)accs[grp])[lane32] = acc;
    __syncthreads();

    float* P = part + ((size_t)bh * nsplit + split) * (DHEAD + 2);
    if (tid < DHEAD) {
        float a = 0.f;
        #pragma unroll
        for (int g = 0; g < 8; ++g) a += accs[g][tid];
        P[tid] = a;
    }
    if (tid == 0) { P[DHEAD] = m; P[DHEAD + 1] = lsum; }
}

// ---------------------------------------------------------------------------
// Kernel 2: combine splits (log-sum-exp merge), write attn as [B, H*D].
// ---------------------------------------------------------------------------
__global__ __launch_bounds__(DHEAD) void attn_combine(
    const float* __restrict__ part, float* __restrict__ attn,
    int nsplit, int H)
{
    const int bh  = blockIdx.x;
    const int tid = threadIdx.x;        // 0..127
    const float* P = part + (size_t)bh * nsplit * (DHEAD + 2);

    float m = -INFINITY;
    for (int s = 0; s < nsplit; ++s)
        m = fmaxf(m, P[s * (DHEAD + 2) + DHEAD]);

    float l = 0.f, a = 0.f;
    for (int s = 0; s < nsplit; ++s) {
        const float w = expf(P[s * (DHEAD + 2) + DHEAD] - m);
        l += P[s * (DHEAD + 2) + DHEAD + 1] * w;
        a += P[s * (DHEAD + 2) + tid] * w;
    }
    attn[(size_t)bh * DHEAD + tid] = a / l;   // bh*128 == b*(H*D) + h*D: same order
}

// ---------------------------------------------------------------------------
// Kernel 3: out[b][j] = bias[j] + attn[b,:] . W[j,:]   (torch Linear: x @ W^T)
// One block per output column j; W row streamed once; 8 batch accs in regs.
// ---------------------------------------------------------------------------
__global__ __launch_bounds__(TPB) void out_proj(
    const float* __restrict__ attn, const float* __restrict__ W,
    const float* __restrict__ bias, float* __restrict__ out, int HD)
{
    const int j   = blockIdx.x;
    const int tid = threadIdx.x;
    const float4* Wr = (const float4*)(W + (size_t)j * HD);
    const int nv = HD >> 2;             // 1024 float4s per row

    float acc[NB];
    #pragma unroll
    for (int b = 0; b < NB; ++b) acc[b] = 0.f;

    for (int i = tid; i < nv; i += TPB) {
        const float4 w4 = Wr[i];
        #pragma unroll
        for (int b = 0; b < NB; ++b) {
            const float4 a4 = ((const float4*)attn)[(size_t)b * nv + i];
            acc[b] += w4.x * a4.x + w4.y * a4.y + w4.z * a4.z + w4.w * a4.w;
        }
    }

    #pragma unroll
    for (int b = 0; b < NB; ++b) {
        #pragma unroll
        for (int off = 32; off > 0; off >>= 1)
            acc[b] += __shfl_xor(acc[b], off);
    }

    __shared__ float red[4][NB];
    if ((tid & 63) == 0) {
        #pragma unroll
        for (int b = 0; b < NB; ++b) red[tid >> 6][b] = acc[b];
    }
    __syncthreads();
    if (tid < NB) {
        const float r = red[0][tid] + red[1][tid] + red[2][tid] + red[3][tid];
        out[(size_t)tid * HD + j] = r + bias[j];
    }
}

// ---------------------------------------------------------------------------
extern "C" void kernel_launch(void* const* d_in, const int* in_sizes, int n_in,
                              void* d_out, int out_size, void* d_ws, size_t ws_size,
                              hipStream_t stream)
{
    const float* q    = (const float*)d_in[0];
    const float* kc   = (const float*)d_in[1];
    const float* vc   = (const float*)d_in[2];
    const float* W    = (const float*)d_in[3];
    const float* bias = (const float*)d_in[4];
    float* out = (float*)d_out;

    const int HD = in_sizes[4];                 // H*D = 4096
    const int B  = in_sizes[0] / HD;            // 8
    const int H  = HD / DHEAD;                  // 32
    const int S  = in_sizes[1] / in_sizes[0];   // 8192
    const int BH = B * H;                       // 256
    const int nsplit = S / CHUNK;               // 8

    float* part = (float*)d_ws;                            // BH*nsplit*130 floats (~1 MB)
    float* attn = part + (size_t)BH * nsplit * (DHEAD + 2); // B*HD floats (128 KB)

    attn_partial<<<dim3(BH, nsplit), TPB, 0, stream>>>(q, kc, vc, part, S, nsplit);
    attn_combine<<<BH, DHEAD, 0, stream>>>(part, attn, nsplit, H);
    out_proj<<<HD, TPB, 0, stream>>>(attn, W, bias, out, HD);
}